// Round 6
// baseline (341.364 us; speedup 1.0000x reference)
//
#include <hip/hip_runtime.h>
#include <hip/hip_fp16.h>
#include <stdint.h>

#define Bn 32
#define Cc 64
#define Hh 112
#define Ww 112
#define HWp (Hh*Ww)            // 12544
#define ALPHA 0.25f

#define TS 16                  // tile size (interior pixels per side)
#define NT 7                   // tiles per image side (112/16)
#define RA 20                  // bits1 region side (TS+4)
#define RB 18                  // bits2 region side (TS+2)

typedef _Float16 f16x2 __attribute__((ext_vector_type(2)));

// workspace layout (bytes) — tables only; no big intermediates anymore
#define WB1_OFF   0                      // uint64[64*9]
#define WB2_OFF   4608
#define ASC1_OFF  9216                   // float[64]  (= ALPHA * mean|w|)
#define ASC2_OFF  9472
#define CI1_OFF   9728                   // int[64*10] (padded stride 10)
#define CI2_OFF   12288                  // int[64*10]

// Compiler memory barrier: loads issued before it cannot sink past it,
// so a preload batch is guaranteed in flight under the following compute.
#define MEMFENCE() asm volatile("" ::: "memory")

__device__ __forceinline__ int dot9(const uint64_t* q, const uint64_t* __restrict__ wo) {
    int s = 0;
    #pragma unroll
    for (int k = 0; k < 9; ++k) s += (int)__popcll(q[k] ^ wo[k]);
    return s;
}

// 128 blocks x 64 lanes; block b<64 -> conv1 tables (o=b), else conv2.
__global__ __launch_bounds__(64) void prep_weights(
        const float* __restrict__ w3, const float* __restrict__ wpw,
        uint64_t* __restrict__ wb1, uint64_t* __restrict__ wb2,
        float* __restrict__ asc1, float* __restrict__ asc2,
        int* __restrict__ ci1, int* __restrict__ ci2) {
    int b = blockIdx.x;
    int lane = threadIdx.x;
    const float* w  = (b < 64) ? w3   : wpw;
    uint64_t* wbits = (b < 64) ? wb1  : wb2;
    float*    ascp  = (b < 64) ? asc1 : asc2;
    int*      cip   = (b < 64) ? ci1  : ci2;
    int o = b & 63;
    const float* wp = w + ((size_t)o * Cc + lane) * 9;
    float v[9]; float asum = 0.f;
    #pragma unroll
    for (int t = 0; t < 9; ++t) { v[t] = wp[t]; asum += fabsf(v[t]); }
    uint64_t bal[9];
    #pragma unroll
    for (int t = 0; t < 9; ++t) bal[t] = __ballot(v[t] < 0.f);
    if (lane < 9) {
        wbits[o * 9 + lane] = bal[lane];
        int ty = lane, tr = ty / 3, tc = ty % 3;
        int sum = 0;
        #pragma unroll
        for (int t = 0; t < 9; ++t) {
            int r = t / 3, c = t % 3;
            bool inv = (tr == 0 && r == 0) || (tr == 2 && r == 2) ||
                       (tc == 0 && c == 0) || (tc == 2 && c == 2);
            if (inv) sum += 64 - 2 * (int)__popcll(bal[t]);
        }
        cip[o * 10 + ty] = 576 - sum;       // padded stride 10
    }
    #pragma unroll
    for (int off = 32; off > 0; off >>= 1) asum += __shfl_down(asum, off, 64);
    if (lane == 0) ascp[o] = ALPHA * asum * (1.f / 576.f);
}

// Fully fused block: pack(20x20) -> conv1(18x18, residual in regs, bits2 in LDS)
// -> conv2(16x16 interior) -> out.  One block per tile per image.
__global__ __launch_bounds__(256, 4) void fused(
        const float* __restrict__ x,
        const uint64_t* __restrict__ wb1, const uint64_t* __restrict__ wb2,
        const float* __restrict__ asc1, const float* __restrict__ asc2,
        const int* __restrict__ ci1, const int* __restrict__ ci2,
        const float* __restrict__ b11,
        const float* __restrict__ b12, const float* __restrict__ a1,
        const float* __restrict__ b13, const float* __restrict__ b21,
        const float* __restrict__ b22, const float* __restrict__ a2,
        const float* __restrict__ b23,
        float* __restrict__ out) {
    __shared__ uint64_t lb1[RA * RA];          // bits1, region (h0-2.., w0-2..)
    __shared__ uint64_t lb2[RB * RB];          // bits2, region (h0-1.., w0-1..)
    __shared__ int lc1[Cc * 10];               // cint tables, stride 10
    __shared__ int lc2[Cc * 10];

    int tid = threadIdx.x;
    int bx = blockIdx.x;                       // 0..48
    int n  = blockIdx.y;
    int tyy = bx / NT, txx = bx - tyy * NT;
    int h0 = tyy * TS, w0 = txx * TS;

    for (int i = tid; i < Cc * 10; i += 256) { lc1[i] = ci1[i]; lc2[i] = ci2[i]; }

    const float* xn = x + (size_t)n * Cc * HWp;

    // ---------- phase A: bits1 over RA x RA ----------
    #pragma unroll
    for (int it = 0; it < 2; ++it) {
        int idx = tid + it * 256;
        if (idx < RA * RA) {
            int ai = idx / RA, aj = idx - ai * RA;
            int ph = h0 - 2 + ai, pw = w0 - 2 + aj;
            uint64_t m = 0;
            if ((unsigned)ph < (unsigned)Hh && (unsigned)pw < (unsigned)Ww) {
                const float* xp = xn + ph * Ww + pw;
                float v[32];
                #pragma unroll
                for (int j = 0; j < 32; ++j) v[j] = xp[(size_t)j * HWp];
                MEMFENCE();
                #pragma unroll
                for (int j = 0; j < 32; ++j)
                    if (v[j] + b11[j] < 0.f) m |= (1ull << j);
                #pragma unroll
                for (int j = 0; j < 32; ++j) v[j] = xp[(size_t)(32 + j) * HWp];
                MEMFENCE();
                #pragma unroll
                for (int j = 0; j < 32; ++j)
                    if (v[j] + b11[32 + j] < 0.f) m |= (1ull << (32 + j));
            }
            lb1[idx] = m;
        }
    }
    __syncthreads();

    // ---------- phase B: conv1 ----------
    int py = tid >> 4, px = tid & 15;          // this thread's interior pixel
    int ph = h0 + py, pw = w0 + px;            // always in-image (112 % 16 == 0)
    int t9i = ((ph == 0) ? 0 : (ph == Hh - 1) ? 6 : 3) +
              ((pw == 0) ? 0 : (pw == Ww - 1) ? 2 : 1);

    f16x2 res[32];                             // out1 residual, statically indexed
    {
        int bi = py + 1, bj = px + 1;          // cell in B region
        uint64_t q[9];
        #pragma unroll
        for (int r = 0; r < 3; ++r)
            #pragma unroll
            for (int c = 0; c < 3; ++c)
                q[r * 3 + c] = lb1[(bi + r) * RA + (bj + c)];

        const float* xp = xn + ph * Ww + pw;
        uint64_t m2 = 0;
        #pragma unroll
        for (int oc = 0; oc < Cc; oc += 8) {
            float xv[8];
            #pragma unroll
            for (int j = 0; j < 8; ++j) xv[j] = xp[(size_t)(oc + j) * HWp];
            MEMFENCE();
            #pragma unroll
            for (int j = 0; j < 8; ++j) {
                int ch = oc + j;
                int s = dot9(q, wb1 + ch * 9); // wave-uniform weight addr -> s_load
                int m = lc1[ch * 10 + t9i] - (s << 1);
                float v = fmaf(asc1[ch], (float)m, xv[j]);
                v += b12[ch];
                v = fmaf(fminf(v, 0.f), a1[ch] - 1.0f, v);   // prelu
                v += b13[ch];
                if (j & 1) res[ch >> 1].y = (_Float16)v;
                else       res[ch >> 1].x = (_Float16)v;
                if (v + b21[ch] < 0.f) m2 |= (1ull << ch);
            }
        }
        lb2[bi * RB + bj] = m2;
    }

    // ring pixels of the B region (68 cells): sign-only conv1
    if (tid < 2 * RB + 2 * (RB - 2)) {         // 68
        int ri, rj;
        if      (tid < RB)          { ri = 0;            rj = tid; }
        else if (tid < 2 * RB)      { ri = RB - 1;       rj = tid - RB; }
        else if (tid < 2 * RB + 16) { ri = tid - 2 * RB + 1;      rj = 0; }
        else                        { ri = tid - (2 * RB + 16) + 1; rj = RB - 1; }
        int rph = h0 - 1 + ri, rpw = w0 - 1 + rj;
        uint64_t m2 = 0;
        if ((unsigned)rph < (unsigned)Hh && (unsigned)rpw < (unsigned)Ww) {
            int t9r = ((rph == 0) ? 0 : (rph == Hh - 1) ? 6 : 3) +
                      ((rpw == 0) ? 0 : (rpw == Ww - 1) ? 2 : 1);
            uint64_t q[9];
            #pragma unroll
            for (int r = 0; r < 3; ++r)
                #pragma unroll
                for (int c = 0; c < 3; ++c)
                    q[r * 3 + c] = lb1[(ri + r) * RA + (rj + c)];
            const float* xp = xn + rph * Ww + rpw;
            #pragma unroll 1
            for (int oc = 0; oc < Cc; oc += 8) {
                float xv[8];
                #pragma unroll
                for (int j = 0; j < 8; ++j) xv[j] = xp[(size_t)(oc + j) * HWp];
                MEMFENCE();
                #pragma unroll
                for (int j = 0; j < 8; ++j) {
                    int ch = oc + j;
                    int s = dot9(q, wb1 + ch * 9);
                    int m = lc1[ch * 10 + t9r] - (s << 1);
                    float v = fmaf(asc1[ch], (float)m, xv[j]);
                    v += b12[ch];
                    v = fmaf(fminf(v, 0.f), a1[ch] - 1.0f, v);
                    v += b13[ch];
                    if (v + b21[ch] < 0.f) m2 |= (1ull << ch);
                }
            }
        }
        lb2[ri * RB + rj] = m2;
    }
    __syncthreads();

    // ---------- phase C: conv2 on interior, residual from regs ----------
    {
        uint64_t q[9];
        #pragma unroll
        for (int r = 0; r < 3; ++r)
            #pragma unroll
            for (int c = 0; c < 3; ++c)
                q[r * 3 + c] = lb2[(py + r) * RB + (px + c)];

        float* op = out + (size_t)n * Cc * HWp + ph * Ww + pw;
        #pragma unroll
        for (int oc = 0; oc < Cc; oc += 8) {
            #pragma unroll
            for (int j = 0; j < 8; ++j) {
                int ch = oc + j;
                int s = dot9(q, wb2 + ch * 9);
                int m = lc2[ch * 10 + t9i] - (s << 1);
                float r = (j & 1) ? (float)res[ch >> 1].y : (float)res[ch >> 1].x;
                float v = fmaf(asc2[ch], (float)m, r);
                v += b22[ch];
                v = fmaf(fminf(v, 0.f), a2[ch] - 1.0f, v);
                v += b23[ch];
                __builtin_nontemporal_store(v, op + (size_t)ch * HWp);
            }
        }
    }
}

extern "C" void kernel_launch(void* const* d_in, const int* in_sizes, int n_in,
                              void* d_out, int out_size, void* d_ws, size_t ws_size,
                              hipStream_t stream) {
    const float* x    = (const float*)d_in[0];
    const float* w3   = (const float*)d_in[1];
    const float* wpw  = (const float*)d_in[2];
    const float* b11  = (const float*)d_in[3];
    const float* b12  = (const float*)d_in[4];
    const float* b13  = (const float*)d_in[5];
    const float* b21  = (const float*)d_in[6];
    const float* b22  = (const float*)d_in[7];
    const float* b23  = (const float*)d_in[8];
    const float* a1   = (const float*)d_in[9];
    const float* a2   = (const float*)d_in[10];

    char* ws = (char*)d_ws;
    uint64_t* wb1   = (uint64_t*)(ws + WB1_OFF);
    uint64_t* wb2   = (uint64_t*)(ws + WB2_OFF);
    float*    asc1  = (float*)(ws + ASC1_OFF);
    float*    asc2  = (float*)(ws + ASC2_OFF);
    int*      ci1   = (int*)(ws + CI1_OFF);
    int*      ci2   = (int*)(ws + CI2_OFF);
    float*    out   = (float*)d_out;

    prep_weights<<<128, 64, 0, stream>>>(w3, wpw, wb1, wb2, asc1, asc2, ci1, ci2);

    dim3 fgrid(NT * NT, Bn);                   // 49 x 32 = 1568 blocks
    fused<<<fgrid, 256, 0, stream>>>(x, wb1, wb2, asc1, asc2, ci1, ci2,
                                     b11, b12, a1, b13, b21, b22, a2, b23, out);
}